// Round 13
// baseline (169.893 us; speedup 1.0000x reference)
//
#include <hip/hip_runtime.h>

#define NTOK 49
#define NH 4
#define HD 32
#define CIN 384
#define NW 64
#define NPAD 64
#define SCALE_F 0.1767766952966369f

typedef _Float16 f16x8 __attribute__((ext_vector_type(8)));
typedef float f32x16 __attribute__((ext_vector_type(16)));
typedef __fp16 fp16x2 __attribute__((ext_vector_type(2)));

__device__ __forceinline__ unsigned int pkh(float a, float b) {
    fp16x2 h = __builtin_amdgcn_cvt_pkrtz(a, b);
    return __builtin_bit_cast(unsigned int, h);
}

// cmT[w*4+h][j][i] = mask[h][i][j] + rot[w][i][j], padded to 64x64,
// j>=49 -> -1e30 (kills padded keys in softmax), i>=49 -> 0.
__global__ __launch_bounds__(64) void prep_cmask(
    const float* __restrict__ mask,
    const float* __restrict__ rot,
    float* __restrict__ cmT)
{
    const int wh = blockIdx.x;          // w*4 + h
    const int w = wh >> 2, h = wh & 3;
    const int i = threadIdx.x;          // 0..63
    for (int j = 0; j < NPAD; ++j) {
        float v;
        if (j >= NTOK) v = -1e30f;
        else if (i >= NTOK) v = 0.f;
        else v = mask[(h * NTOK + i) * NTOK + j] + rot[(w * NTOK + i) * NTOK + j];
        cmT[((size_t)wh * NPAD + j) * NPAD + i] = v;
    }
}

// Two problems per 2-wave block, T14-pipelined: stage A into LDS[0]; ISSUE B's
// global loads into registers; compute A; then cvt+ds_write B into LDS[1]
// (loads long arrived); barrier; compute B. Per-problem math is the proven R9
// kernel verbatim: wave it owns query-half it; S^T = K*Q^T via mfma_32x32x16_f16
// (C: col=i=lane&31, row=j=(r&3)+8*(r>>2)+4*hl+32*jt); softmax lane-local +
// shfl_xor(32); P packed via cvt_pkrtz + one lane^32 exchange.
template<bool USE_CM>
__global__ __launch_bounds__(128) void win_attn_mfma(
    const float* __restrict__ qkv,
    const float* __restrict__ mask,
    const float* __restrict__ rot,
    const float* __restrict__ cmT,
    float* __restrict__ out)
{
    const int tid = threadIdx.x;
    const int it = tid >> 6;            // wave id = query-half
    const int lane = tid & 63;
    const int l31 = lane & 31;
    const int hl = lane >> 5;
    const int i = l31 + 32 * it;

    __shared__ _Float16 Qs[2][NPAD * HD];   // rows >= 49 zeroed
    __shared__ _Float16 Ks[2][NPAD * HD];

    const int pA = blockIdx.x * 2;
    const int pB = pA + 1;
    const int hA = pA & 3, bA = pA >> 2, wA = bA & (NW - 1);
    const int hB = pB & 3, bB = pB >> 2, wB = bB & (NW - 1);

    const float* baseA = qkv + (size_t)bA * (NTOK * CIN) + hA * HD;
    const float* baseB = qkv + (size_t)bB * (NTOK * CIN) + hB * HD;

    // ---- stage A into LDS[0] (R9 verbatim: load/cvt/write interleaved) ----
    #pragma unroll
    for (int t4 = 0; t4 < 4; ++t4) {
        const int idx = tid + t4 * 128;    // 0..511
        const int n = idx >> 3;            // row 0..63
        const int c = idx & 7;             // float4 chunk
        float4 fq = make_float4(0.f, 0.f, 0.f, 0.f);
        float4 fk = fq;
        if (n < NTOK) {
            const float* pp = baseA + n * CIN + c * 4;
            fq = *reinterpret_cast<const float4*>(pp);
            fk = *reinterpret_cast<const float4*>(pp + 128);
        }
        uint2 uq, uk;
        uq.x = pkh(fq.x * SCALE_F, fq.y * SCALE_F);
        uq.y = pkh(fq.z * SCALE_F, fq.w * SCALE_F);
        uk.x = pkh(fk.x, fk.y);
        uk.y = pkh(fk.z, fk.w);
        *reinterpret_cast<uint2*>(&Qs[0][n * HD + c * 4]) = uq;
        *reinterpret_cast<uint2*>(&Ks[0][n * HD + c * 4]) = uk;
    }

    // ---- ISSUE B's global loads into registers (consumed after compute A) ----
    float4 bq[4], bk[4];
    #pragma unroll
    for (int t4 = 0; t4 < 4; ++t4) {
        const int idx = tid + t4 * 128;
        const int n = idx >> 3;
        const int c = idx & 7;
        bq[t4] = make_float4(0.f, 0.f, 0.f, 0.f);
        bk[t4] = bq[t4];
        if (n < NTOK) {
            const float* pp = baseB + n * CIN + c * 4;
            bq[t4] = *reinterpret_cast<const float4*>(pp);
            bk[t4] = *reinterpret_cast<const float4*>(pp + 128);
        }
    }

    // ---- combined-mask loader (per problem) ----
    auto load_cm = [&](int w, int h, float cm[2][16]) {
        #pragma unroll
        for (int jt = 0; jt < 2; ++jt) {
            #pragma unroll
            for (int r = 0; r < 16; ++r) {
                const int j = (r & 3) + 8 * (r >> 2) + 4 * hl + 32 * jt;
                if (USE_CM) {
                    cm[jt][r] = cmT[((size_t)(w * 4 + h) * NPAD + j) * NPAD + i];
                } else {
                    float v;
                    if (j >= NTOK) v = -1e30f;
                    else if (i >= NTOK) v = 0.f;
                    else v = mask[(h * NTOK + i) * NTOK + j] + rot[(w * NTOK + i) * NTOK + j];
                    cm[jt][r] = v;
                }
            }
        }
    };

    // ---- per-problem compute (R9 verbatim), s = LDS buffer ----
    auto compute = [&](int s, int b, int h, const float cm[2][16]) {
        f16x8 ka[2][2], qa[2];
        #pragma unroll
        for (int kt = 0; kt < 2; ++kt) {
            #pragma unroll
            for (int ks = 0; ks < 2; ++ks) {
                ka[kt][ks] = *reinterpret_cast<const f16x8*>(&Ks[s][(l31 + 32 * kt) * HD + ks * 16 + hl * 8]);
            }
        }
        #pragma unroll
        for (int ks = 0; ks < 2; ++ks) {
            qa[ks] = *reinterpret_cast<const f16x8*>(&Qs[s][(l31 + 32 * it) * HD + ks * 16 + hl * 8]);
        }

        f32x16 acc[2];
        #pragma unroll
        for (int jt = 0; jt < 2; ++jt) {
            f32x16 a;
            #pragma unroll
            for (int r = 0; r < 16; ++r) a[r] = 0.f;
            a = __builtin_amdgcn_mfma_f32_32x32x16_f16(ka[jt][0], qa[0], a, 0, 0, 0);
            a = __builtin_amdgcn_mfma_f32_32x32x16_f16(ka[jt][1], qa[1], a, 0, 0, 0);
            acc[jt] = a;
        }

        float m = -3e38f;
        #pragma unroll
        for (int jt = 0; jt < 2; ++jt) {
            #pragma unroll
            for (int r = 0; r < 16; ++r) {
                acc[jt][r] += cm[jt][r];
                m = fmaxf(m, acc[jt][r]);
            }
        }
        m = fmaxf(m, __shfl_xor(m, 32));
        float sum = 0.f;
        #pragma unroll
        for (int jt = 0; jt < 2; ++jt) {
            #pragma unroll
            for (int r = 0; r < 16; ++r) {
                const float e = __expf(acc[jt][r] - m);
                acc[jt][r] = e;
                sum += e;
            }
        }
        sum += __shfl_xor(sum, 32);
        const float inv = 1.f / sum;
        #pragma unroll
        for (int jt = 0; jt < 2; ++jt) {
            #pragma unroll
            for (int r = 0; r < 16; ++r) acc[jt][r] *= inv;
        }

        f32x16 oacc;
        #pragma unroll
        for (int r = 0; r < 16; ++r) oacc[r] = 0.f;

        #pragma unroll
        for (int ks = 0; ks < 4; ++ks) {
            unsigned int vd[4];
            #pragma unroll
            for (int ep = 0; ep < 4; ++ep) {
                const int j0 = 16 * ks + 8 * hl + 2 * ep;
                float v0 = 0.f, v1 = 0.f;
                if (j0 < NTOK)
                    v0 = qkv[((size_t)b * NTOK + j0) * CIN + 256 + h * HD + l31];
                if (j0 + 1 < NTOK)
                    v1 = qkv[((size_t)b * NTOK + j0 + 1) * CIN + 256 + h * HD + l31];
                vd[ep] = pkh(v0, v1);
            }
            uint4 vu = make_uint4(vd[0], vd[1], vd[2], vd[3]);
            const f16x8 vb = __builtin_bit_cast(f16x8, vu);

            const int jt = ks >> 1;
            const int r8 = 8 * (ks & 1);
            const unsigned lo0 = pkh(acc[jt][r8 + 0], acc[jt][r8 + 1]);
            const unsigned lo1 = pkh(acc[jt][r8 + 2], acc[jt][r8 + 3]);
            const unsigned hi0 = pkh(acc[jt][r8 + 4], acc[jt][r8 + 5]);
            const unsigned hi1 = pkh(acc[jt][r8 + 6], acc[jt][r8 + 7]);
            const unsigned x0 = hl ? lo0 : hi0;
            const unsigned x1 = hl ? lo1 : hi1;
            const unsigned y0 = (unsigned)__shfl_xor((int)x0, 32);
            const unsigned y1 = (unsigned)__shfl_xor((int)x1, 32);
            uint4 pu;
            pu.x = hl ? y0 : lo0;
            pu.y = hl ? y1 : lo1;
            pu.z = hl ? hi0 : y0;
            pu.w = hl ? hi1 : y1;
            const f16x8 pa = __builtin_bit_cast(f16x8, pu);
            oacc = __builtin_amdgcn_mfma_f32_32x32x16_f16(pa, vb, oacc, 0, 0, 0);
        }

        float* obase = out + (size_t)b * NTOK * (NH * HD) + h * HD + l31;
        #pragma unroll
        for (int r = 0; r < 16; ++r) {
            const int io = (r & 3) + 8 * (r >> 2) + 4 * hl + 32 * it;
            if (io < NTOK) obase[(size_t)io * (NH * HD)] = oacc[r];
        }
    };

    // ---- A: cm, barrier, compute ----
    float cmA[2][16];
    load_cm(wA, hA, cmA);

    __syncthreads();
    compute(0, bA, hA, cmA);

    // ---- write B into LDS[1] (loads arrived during compute A) ----
    #pragma unroll
    for (int t4 = 0; t4 < 4; ++t4) {
        const int idx = tid + t4 * 128;
        const int n = idx >> 3;
        const int c = idx & 7;
        uint2 uq, uk;
        uq.x = pkh(bq[t4].x * SCALE_F, bq[t4].y * SCALE_F);
        uq.y = pkh(bq[t4].z * SCALE_F, bq[t4].w * SCALE_F);
        uk.x = pkh(bk[t4].x, bk[t4].y);
        uk.y = pkh(bk[t4].z, bk[t4].w);
        *reinterpret_cast<uint2*>(&Qs[1][n * HD + c * 4]) = uq;
        *reinterpret_cast<uint2*>(&Ks[1][n * HD + c * 4]) = uk;
    }

    float cmB[2][16];
    load_cm(wB, hB, cmB);

    __syncthreads();
    compute(1, bB, hB, cmB);
}

extern "C" void kernel_launch(void* const* d_in, const int* in_sizes, int n_in,
                              void* d_out, int out_size, void* d_ws, size_t ws_size,
                              hipStream_t stream) {
    const float* qkv  = (const float*)d_in[0];
    const float* mask = (const float*)d_in[1];
    const float* rot  = (const float*)d_in[2];
    float* out = (float*)d_out;

    const int Btot = in_sizes[0] / (NTOK * CIN);  // 4096
    const int nprob = Btot * NH;                  // 16384
    dim3 grid(nprob / 2);                         // 8192 blocks, 2 problems each

    const size_t cm_bytes = (size_t)NW * NH * NPAD * NPAD * sizeof(float);  // 4 MiB
    if (ws_size >= cm_bytes && d_ws != nullptr) {
        float* cmT = (float*)d_ws;
        prep_cmask<<<dim3(NW * NH), 64, 0, stream>>>(mask, rot, cmT);
        win_attn_mfma<true><<<grid, 128, 0, stream>>>(qkv, mask, rot, cmT, out);
    } else {
        win_attn_mfma<false><<<grid, 128, 0, stream>>>(qkv, mask, rot, nullptr, out);
    }
}

// Round 15
// 105.173 us; speedup vs baseline: 1.6154x; 1.6154x over previous
//
#include <hip/hip_runtime.h>

#define NTOK 49
#define NH 4
#define HD 32
#define CIN 384
#define NW 64
#define NPAD 64
#define SCALE_F 0.1767766952966369f

typedef _Float16 f16x8 __attribute__((ext_vector_type(8)));
typedef float f32x16 __attribute__((ext_vector_type(16)));
typedef __fp16 fp16x2 __attribute__((ext_vector_type(2)));

__device__ __forceinline__ unsigned int pkh(float a, float b) {
    fp16x2 h = __builtin_amdgcn_cvt_pkrtz(a, b);
    return __builtin_bit_cast(unsigned int, h);
}

__device__ __forceinline__ void gload16(const float* g, float* l) {
    __builtin_amdgcn_global_load_lds(
        (const __attribute__((address_space(1))) void*)g,
        (__attribute__((address_space(3))) void*)l, 16, 0, 0);
}

// cmT[w*4+h][j][i] = mask[h][i][j] + rot[w][i][j], padded to 64x64,
// j>=49 -> -1e30 (kills padded keys in softmax), i>=49 -> 0.
__global__ __launch_bounds__(64) void prep_cmask(
    const float* __restrict__ mask,
    const float* __restrict__ rot,
    float* __restrict__ cmT)
{
    const int wh = blockIdx.x;          // w*4 + h
    const int w = wh >> 2, h = wh & 3;
    const int i = threadIdx.x;          // 0..63
    for (int j = 0; j < NPAD; ++j) {
        float v;
        if (j >= NTOK) v = -1e30f;
        else if (i >= NTOK) v = 0.f;
        else v = mask[(h * NTOK + i) * NTOK + j] + rot[(w * NTOK + i) * NTOK + j];
        cmT[((size_t)wh * NPAD + j) * NPAD + i] = v;
    }
}

// R9 shell + global_load_lds staging. LDS holds f32 Q/K [64][32] with a
// chunk-XOR swizzle realized by PRE-SWIZZLING the per-lane global source
// (gload_lds dest is wave-uniform base + lane*16B, linear). One instruction
// covers 8 rows (64 lanes x 16B = 8 rows x 128B): lane l -> row 8g+(l>>3),
// phys chunk l&7, sourced from logical chunk (l&7)^(l>>3). Read side XORs the
// same way (swz = row&7). Tail g=6: source row clamped to 48 (dup data is
// finite; cm[j>=49]=-1e30 kills it). Rows 56..63 zero-filled by ds_write.
// Wave it owns query-half it; S^T=K*Q^T via mfma_32x32x16_f16
// (C: col=i=lane&31, row=j=(r&3)+8*(r>>2)+4*hl+32*jt); softmax lane-local +
// shfl_xor(32); P packed via cvt_pkrtz + one lane^32 exchange (R9 verbatim).
template<bool USE_CM>
__global__ __launch_bounds__(128) void win_attn_mfma(
    const float* __restrict__ qkv,
    const float* __restrict__ mask,
    const float* __restrict__ rot,
    const float* __restrict__ cmT,
    float* __restrict__ out)
{
    const int h = blockIdx.x & 3;
    const int b = blockIdx.x >> 2;
    const int w = b & (NW - 1);
    const int tid = threadIdx.x;
    const int it = tid >> 6;            // wave id = query-half (0 stages Q, 1 stages K)
    const int lane = tid & 63;
    const int l31 = lane & 31;
    const int hl = lane >> 5;
    const int i = l31 + 32 * it;

    __shared__ float Qf[NPAD * 32];     // f32, swizzled-chunk layout
    __shared__ float Kf[NPAD * 32];

    // ---- zero-fill rows 56..63 (floats 1792..2047) of both arrays ----
    {
        const float4 z4 = make_float4(0.f, 0.f, 0.f, 0.f);
        if (tid < 64) *reinterpret_cast<float4*>(&Qf[1792 + tid * 4]) = z4;
        else          *reinterpret_cast<float4*>(&Kf[1792 + (tid - 64) * 4]) = z4;
    }

    // ---- fire-and-forget staging: wave 0 -> Q, wave 1 -> K ----
    {
        const int row_l = lane >> 3;            // 0..7
        const int clog = (lane & 7) ^ row_l;    // pre-swizzled source chunk
        const float* srcbase = qkv + (size_t)b * (NTOK * CIN)
                             + (it ? 128 : 0) + h * HD + clog * 4;
        float* dst = it ? Kf : Qf;
        #pragma unroll
        for (int g = 0; g < 7; ++g) {
            const int srcrow = (8 * g + row_l < NTOK) ? (8 * g + row_l) : 48;
            gload16(srcbase + (size_t)srcrow * CIN, dst + g * 256);
        }
    }

    // ---- combined mask values (pre-barrier; latency rides under stage drain) ----
    float cm[2][16];
    #pragma unroll
    for (int jt = 0; jt < 2; ++jt) {
        #pragma unroll
        for (int r = 0; r < 16; ++r) {
            const int j = (r & 3) + 8 * (r >> 2) + 4 * hl + 32 * jt;
            if (USE_CM) {
                cm[jt][r] = cmT[((size_t)(w * 4 + h) * NPAD + j) * NPAD + i];
            } else {
                float v;
                if (j >= NTOK) v = -1e30f;
                else if (i >= NTOK) v = 0.f;
                else v = mask[(h * NTOK + i) * NTOK + j] + rot[(w * NTOK + i) * NTOK + j];
                cm[jt][r] = v;
            }
        }
    }

    __syncthreads();

    // ---- fragments from LDS (swizzled chunks), cvt to f16 at build ----
    auto ldfrag = [&](const float* L, int row, int ks, bool scaled) -> f16x8 {
        const int swz = row & 7;
        const int c0 = ks * 4 + hl * 2;
        const float4 a  = *reinterpret_cast<const float4*>(&L[row * 32 + ((c0)     ^ swz) * 4]);
        const float4 bb = *reinterpret_cast<const float4*>(&L[row * 32 + ((c0 + 1) ^ swz) * 4]);
        uint4 u;
        if (scaled) {
            u.x = pkh(a.x * SCALE_F, a.y * SCALE_F);
            u.y = pkh(a.z * SCALE_F, a.w * SCALE_F);
            u.z = pkh(bb.x * SCALE_F, bb.y * SCALE_F);
            u.w = pkh(bb.z * SCALE_F, bb.w * SCALE_F);
        } else {
            u.x = pkh(a.x, a.y);
            u.y = pkh(a.z, a.w);
            u.z = pkh(bb.x, bb.y);
            u.w = pkh(bb.z, bb.w);
        }
        return __builtin_bit_cast(f16x8, u);
    };

    f16x8 ka[2][2], qa[2];
    #pragma unroll
    for (int kt = 0; kt < 2; ++kt) {
        #pragma unroll
        for (int ks = 0; ks < 2; ++ks) {
            ka[kt][ks] = ldfrag(Kf, l31 + 32 * kt, ks, false);
        }
    }
    #pragma unroll
    for (int ks = 0; ks < 2; ++ks) {
        qa[ks] = ldfrag(Qf, l31 + 32 * it, ks, true);
    }

    // ---- S^T = K * Q^T for this half ----
    f32x16 acc[2];
    #pragma unroll
    for (int jt = 0; jt < 2; ++jt) {
        f32x16 a;
        #pragma unroll
        for (int r = 0; r < 16; ++r) a[r] = 0.f;
        a = __builtin_amdgcn_mfma_f32_32x32x16_f16(ka[jt][0], qa[0], a, 0, 0, 0);
        a = __builtin_amdgcn_mfma_f32_32x32x16_f16(ka[jt][1], qa[1], a, 0, 0, 0);
        acc[jt] = a;
    }

    // ---- + mask, softmax over j (32 lane-local + lane^32 partner) ----
    float m = -3e38f;
    #pragma unroll
    for (int jt = 0; jt < 2; ++jt) {
        #pragma unroll
        for (int r = 0; r < 16; ++r) {
            acc[jt][r] += cm[jt][r];
            m = fmaxf(m, acc[jt][r]);
        }
    }
    m = fmaxf(m, __shfl_xor(m, 32));
    float s = 0.f;
    #pragma unroll
    for (int jt = 0; jt < 2; ++jt) {
        #pragma unroll
        for (int r = 0; r < 16; ++r) {
            const float e = __expf(acc[jt][r] - m);
            acc[jt][r] = e;
            s += e;
        }
    }
    s += __shfl_xor(s, 32);
    const float inv = 1.f / s;
    #pragma unroll
    for (int jt = 0; jt < 2; ++jt) {
        #pragma unroll
        for (int r = 0; r < 16; ++r) acc[jt][r] *= inv;
    }

    // ---- O = P * V (V fragments from global, R9 verbatim) ----
    f32x16 oacc;
    #pragma unroll
    for (int r = 0; r < 16; ++r) oacc[r] = 0.f;

    #pragma unroll
    for (int ks = 0; ks < 4; ++ks) {
        unsigned int vd[4];
        #pragma unroll
        for (int ep = 0; ep < 4; ++ep) {
            const int j0 = 16 * ks + 8 * hl + 2 * ep;
            float v0 = 0.f, v1 = 0.f;
            if (j0 < NTOK)
                v0 = qkv[((size_t)b * NTOK + j0) * CIN + 256 + h * HD + l31];
            if (j0 + 1 < NTOK)
                v1 = qkv[((size_t)b * NTOK + j0 + 1) * CIN + 256 + h * HD + l31];
            vd[ep] = pkh(v0, v1);
        }
        uint4 vu = make_uint4(vd[0], vd[1], vd[2], vd[3]);
        const f16x8 vb = __builtin_bit_cast(f16x8, vu);

        const int jt = ks >> 1;
        const int r8 = 8 * (ks & 1);
        const unsigned lo0 = pkh(acc[jt][r8 + 0], acc[jt][r8 + 1]);
        const unsigned lo1 = pkh(acc[jt][r8 + 2], acc[jt][r8 + 3]);
        const unsigned hi0 = pkh(acc[jt][r8 + 4], acc[jt][r8 + 5]);
        const unsigned hi1 = pkh(acc[jt][r8 + 6], acc[jt][r8 + 7]);
        const unsigned x0 = hl ? lo0 : hi0;
        const unsigned x1 = hl ? lo1 : hi1;
        const unsigned y0 = (unsigned)__shfl_xor((int)x0, 32);
        const unsigned y1 = (unsigned)__shfl_xor((int)x1, 32);
        uint4 pu;
        pu.x = hl ? y0 : lo0;
        pu.y = hl ? y1 : lo1;
        pu.z = hl ? hi0 : y0;
        pu.w = hl ? hi1 : y1;
        const f16x8 pa = __builtin_bit_cast(f16x8, pu);
        oacc = __builtin_amdgcn_mfma_f32_32x32x16_f16(pa, vb, oacc, 0, 0, 0);
    }

    // ---- store this half: O[i][d], d = l31 ----
    float* obase = out + (size_t)b * NTOK * (NH * HD) + h * HD + l31;
    #pragma unroll
    for (int r = 0; r < 16; ++r) {
        const int io = (r & 3) + 8 * (r >> 2) + 4 * hl + 32 * it;
        if (io < NTOK) obase[(size_t)io * (NH * HD)] = oacc[r];
    }
}

extern "C" void kernel_launch(void* const* d_in, const int* in_sizes, int n_in,
                              void* d_out, int out_size, void* d_ws, size_t ws_size,
                              hipStream_t stream) {
    const float* qkv  = (const float*)d_in[0];
    const float* mask = (const float*)d_in[1];
    const float* rot  = (const float*)d_in[2];
    float* out = (float*)d_out;

    const int Btot = in_sizes[0] / (NTOK * CIN);  // 4096
    dim3 grid(Btot * NH);

    const size_t cm_bytes = (size_t)NW * NH * NPAD * NPAD * sizeof(float);  // 4 MiB
    if (ws_size >= cm_bytes && d_ws != nullptr) {
        float* cmT = (float*)d_ws;
        prep_cmask<<<dim3(NW * NH), 64, 0, stream>>>(mask, rot, cmT);
        win_attn_mfma<true><<<grid, 128, 0, stream>>>(qkv, mask, rot, cmT, out);
    } else {
        win_attn_mfma<false><<<grid, 128, 0, stream>>>(qkv, mask, rot, nullptr, out);
    }
}

// Round 16
// 98.720 us; speedup vs baseline: 1.7209x; 1.0654x over previous
//
#include <hip/hip_runtime.h>

#define NTOK 49
#define NH 4
#define HD 32
#define CIN 384
#define NW 64
#define NPAD 64
#define SCALE_F 0.1767766952966369f

typedef _Float16 f16x8 __attribute__((ext_vector_type(8)));
typedef float f32x16 __attribute__((ext_vector_type(16)));
typedef __fp16 fp16x2 __attribute__((ext_vector_type(2)));

__device__ __forceinline__ unsigned int pkh(float a, float b) {
    fp16x2 h = __builtin_amdgcn_cvt_pkrtz(a, b);
    return __builtin_bit_cast(unsigned int, h);
}

__device__ __forceinline__ void gload16(const float* g, float* l) {
    __builtin_amdgcn_global_load_lds(
        (const __attribute__((address_space(1))) void*)g,
        (__attribute__((address_space(3))) void*)l, 16, 0, 0);
}

// Grouped-quad combined mask: cmQ[wh][jg][i] = float4{ cm(j=4jg+k, i), k=0..3 }
// where cm(j,i) = mask[h][i][j] + rot[w][i][j]; j>=49 -> -1e30, i>=49 -> 0.
// 1024 blocks (4 j-quarters per wh) so prep runs 4 blocks/CU with contiguous reads.
__global__ __launch_bounds__(64) void prep_cmask(
    const float* __restrict__ mask,
    const float* __restrict__ rot,
    float* __restrict__ cmQ)
{
    const int bx = blockIdx.x;          // 0..1023
    const int wh = bx >> 2;             // w*4 + h
    const int qt = bx & 3;              // j-quarter
    const int w = wh >> 2, h = wh & 3;
    const int i = threadIdx.x;          // 0..63
    #pragma unroll
    for (int g = 0; g < 4; ++g) {
        const int jg = qt * 4 + g;
        float4 v;
        float* vp = reinterpret_cast<float*>(&v);
        #pragma unroll
        for (int k = 0; k < 4; ++k) {
            const int j = 4 * jg + k;
            float val;
            if (j >= NTOK) val = -1e30f;
            else if (i >= NTOK) val = 0.f;
            else val = mask[(h * NTOK + i) * NTOK + j] + rot[(w * NTOK + i) * NTOK + j];
            vp[k] = val;
        }
        *reinterpret_cast<float4*>(&cmQ[((size_t)(wh * 16 + jg) * 64 + i) * 4]) = v;
    }
}

// R15 structure: global_load_lds staging of f32 Q/K [64][32] with chunk-XOR
// swizzle via pre-swizzled global source; fragments cvt to f16 at build.
// cm loads are 8 x b128 from the grouped-quad cmQ (was 32 scalar b32).
// Wave it owns query-half it; S^T=K*Q^T via mfma_32x32x16_f16
// (C: col=i=lane&31, row=j=(r&3)+8*(r>>2)+4*hl+32*jt); softmax lane-local +
// shfl_xor(32); P packed via cvt_pkrtz + one lane^32 exchange (R9 verbatim).
template<bool USE_CM>
__global__ __launch_bounds__(128) void win_attn_mfma(
    const float* __restrict__ qkv,
    const float* __restrict__ mask,
    const float* __restrict__ rot,
    const float* __restrict__ cmQ,
    float* __restrict__ out)
{
    const int h = blockIdx.x & 3;
    const int b = blockIdx.x >> 2;
    const int w = b & (NW - 1);
    const int tid = threadIdx.x;
    const int it = tid >> 6;            // wave id = query-half (0 stages Q, 1 stages K)
    const int lane = tid & 63;
    const int l31 = lane & 31;
    const int hl = lane >> 5;
    const int i = l31 + 32 * it;

    __shared__ float Qf[NPAD * 32];     // f32, swizzled-chunk layout
    __shared__ float Kf[NPAD * 32];

    // ---- zero-fill rows 56..63 (floats 1792..2047) of both arrays ----
    {
        const float4 z4 = make_float4(0.f, 0.f, 0.f, 0.f);
        if (tid < 64) *reinterpret_cast<float4*>(&Qf[1792 + tid * 4]) = z4;
        else          *reinterpret_cast<float4*>(&Kf[1792 + (tid - 64) * 4]) = z4;
    }

    // ---- fire-and-forget staging: wave 0 -> Q, wave 1 -> K ----
    {
        const int row_l = lane >> 3;            // 0..7
        const int clog = (lane & 7) ^ row_l;    // pre-swizzled source chunk
        const float* srcbase = qkv + (size_t)b * (NTOK * CIN)
                             + (it ? 128 : 0) + h * HD + clog * 4;
        float* dst = it ? Kf : Qf;
        #pragma unroll
        for (int g = 0; g < 7; ++g) {
            const int srcrow = (8 * g + row_l < NTOK) ? (8 * g + row_l) : 48;
            gload16(srcbase + (size_t)srcrow * CIN, dst + g * 256);
        }
    }

    // ---- combined mask values: 8 x float4 (latency rides under stage drain) ----
    float cm[2][16];
    if (USE_CM) {
        const float* base4 = cmQ + (size_t)(w * 4 + h) * 16 * 256;  // 16 jg x 64 i x 4
        #pragma unroll
        for (int jt = 0; jt < 2; ++jt) {
            #pragma unroll
            for (int rq = 0; rq < 4; ++rq) {
                const int jg = 8 * jt + 2 * rq + hl;
                const float4 c = *reinterpret_cast<const float4*>(&base4[(jg * 64 + i) * 4]);
                cm[jt][4 * rq + 0] = c.x;
                cm[jt][4 * rq + 1] = c.y;
                cm[jt][4 * rq + 2] = c.z;
                cm[jt][4 * rq + 3] = c.w;
            }
        }
    } else {
        #pragma unroll
        for (int jt = 0; jt < 2; ++jt) {
            #pragma unroll
            for (int r = 0; r < 16; ++r) {
                const int j = (r & 3) + 8 * (r >> 2) + 4 * hl + 32 * jt;
                float v;
                if (j >= NTOK) v = -1e30f;
                else if (i >= NTOK) v = 0.f;
                else v = mask[(h * NTOK + i) * NTOK + j] + rot[(w * NTOK + i) * NTOK + j];
                cm[jt][r] = v;
            }
        }
    }

    __syncthreads();

    // ---- fragments from LDS (swizzled chunks), cvt to f16 at build ----
    auto ldfrag = [&](const float* L, int row, int ks, bool scaled) -> f16x8 {
        const int swz = row & 7;
        const int c0 = ks * 4 + hl * 2;
        const float4 a  = *reinterpret_cast<const float4*>(&L[row * 32 + ((c0)     ^ swz) * 4]);
        const float4 bb = *reinterpret_cast<const float4*>(&L[row * 32 + ((c0 + 1) ^ swz) * 4]);
        uint4 u;
        if (scaled) {
            u.x = pkh(a.x * SCALE_F, a.y * SCALE_F);
            u.y = pkh(a.z * SCALE_F, a.w * SCALE_F);
            u.z = pkh(bb.x * SCALE_F, bb.y * SCALE_F);
            u.w = pkh(bb.z * SCALE_F, bb.w * SCALE_F);
        } else {
            u.x = pkh(a.x, a.y);
            u.y = pkh(a.z, a.w);
            u.z = pkh(bb.x, bb.y);
            u.w = pkh(bb.z, bb.w);
        }
        return __builtin_bit_cast(f16x8, u);
    };

    f16x8 ka[2][2], qa[2];
    #pragma unroll
    for (int kt = 0; kt < 2; ++kt) {
        #pragma unroll
        for (int ks = 0; ks < 2; ++ks) {
            ka[kt][ks] = ldfrag(Kf, l31 + 32 * kt, ks, false);
        }
    }
    #pragma unroll
    for (int ks = 0; ks < 2; ++ks) {
        qa[ks] = ldfrag(Qf, l31 + 32 * it, ks, true);
    }

    // ---- S^T = K * Q^T for this half ----
    f32x16 acc[2];
    #pragma unroll
    for (int jt = 0; jt < 2; ++jt) {
        f32x16 a;
        #pragma unroll
        for (int r = 0; r < 16; ++r) a[r] = 0.f;
        a = __builtin_amdgcn_mfma_f32_32x32x16_f16(ka[jt][0], qa[0], a, 0, 0, 0);
        a = __builtin_amdgcn_mfma_f32_32x32x16_f16(ka[jt][1], qa[1], a, 0, 0, 0);
        acc[jt] = a;
    }

    // ---- + mask, softmax over j (32 lane-local + lane^32 partner) ----
    float m = -3e38f;
    #pragma unroll
    for (int jt = 0; jt < 2; ++jt) {
        #pragma unroll
        for (int r = 0; r < 16; ++r) {
            acc[jt][r] += cm[jt][r];
            m = fmaxf(m, acc[jt][r]);
        }
    }
    m = fmaxf(m, __shfl_xor(m, 32));
    float s = 0.f;
    #pragma unroll
    for (int jt = 0; jt < 2; ++jt) {
        #pragma unroll
        for (int r = 0; r < 16; ++r) {
            const float e = __expf(acc[jt][r] - m);
            acc[jt][r] = e;
            s += e;
        }
    }
    s += __shfl_xor(s, 32);
    const float inv = 1.f / s;
    #pragma unroll
    for (int jt = 0; jt < 2; ++jt) {
        #pragma unroll
        for (int r = 0; r < 16; ++r) acc[jt][r] *= inv;
    }

    // ---- O = P * V (V fragments from global, R9 verbatim) ----
    f32x16 oacc;
    #pragma unroll
    for (int r = 0; r < 16; ++r) oacc[r] = 0.f;

    #pragma unroll
    for (int ks = 0; ks < 4; ++ks) {
        unsigned int vd[4];
        #pragma unroll
        for (int ep = 0; ep < 4; ++ep) {
            const int j0 = 16 * ks + 8 * hl + 2 * ep;
            float v0 = 0.f, v1 = 0.f;
            if (j0 < NTOK)
                v0 = qkv[((size_t)b * NTOK + j0) * CIN + 256 + h * HD + l31];
            if (j0 + 1 < NTOK)
                v1 = qkv[((size_t)b * NTOK + j0 + 1) * CIN + 256 + h * HD + l31];
            vd[ep] = pkh(v0, v1);
        }
        uint4 vu = make_uint4(vd[0], vd[1], vd[2], vd[3]);
        const f16x8 vb = __builtin_bit_cast(f16x8, vu);

        const int jt = ks >> 1;
        const int r8 = 8 * (ks & 1);
        const unsigned lo0 = pkh(acc[jt][r8 + 0], acc[jt][r8 + 1]);
        const unsigned lo1 = pkh(acc[jt][r8 + 2], acc[jt][r8 + 3]);
        const unsigned hi0 = pkh(acc[jt][r8 + 4], acc[jt][r8 + 5]);
        const unsigned hi1 = pkh(acc[jt][r8 + 6], acc[jt][r8 + 7]);
        const unsigned x0 = hl ? lo0 : hi0;
        const unsigned x1 = hl ? lo1 : hi1;
        const unsigned y0 = (unsigned)__shfl_xor((int)x0, 32);
        const unsigned y1 = (unsigned)__shfl_xor((int)x1, 32);
        uint4 pu;
        pu.x = hl ? y0 : lo0;
        pu.y = hl ? y1 : lo1;
        pu.z = hl ? hi0 : y0;
        pu.w = hl ? hi1 : y1;
        const f16x8 pa = __builtin_bit_cast(f16x8, pu);
        oacc = __builtin_amdgcn_mfma_f32_32x32x16_f16(pa, vb, oacc, 0, 0, 0);
    }

    // ---- store this half: O[i][d], d = l31 ----
    float* obase = out + (size_t)b * NTOK * (NH * HD) + h * HD + l31;
    #pragma unroll
    for (int r = 0; r < 16; ++r) {
        const int io = (r & 3) + 8 * (r >> 2) + 4 * hl + 32 * it;
        if (io < NTOK) obase[(size_t)io * (NH * HD)] = oacc[r];
    }
}

extern "C" void kernel_launch(void* const* d_in, const int* in_sizes, int n_in,
                              void* d_out, int out_size, void* d_ws, size_t ws_size,
                              hipStream_t stream) {
    const float* qkv  = (const float*)d_in[0];
    const float* mask = (const float*)d_in[1];
    const float* rot  = (const float*)d_in[2];
    float* out = (float*)d_out;

    const int Btot = in_sizes[0] / (NTOK * CIN);  // 4096
    dim3 grid(Btot * NH);

    const size_t cm_bytes = (size_t)NW * NH * 16 * 64 * 4 * sizeof(float);  // 4 MiB
    if (ws_size >= cm_bytes && d_ws != nullptr) {
        float* cmQ = (float*)d_ws;
        prep_cmask<<<dim3(NW * NH * 4), 64, 0, stream>>>(mask, rot, cmQ);
        win_attn_mfma<true><<<grid, 128, 0, stream>>>(qkv, mask, rot, cmQ, out);
    } else {
        win_attn_mfma<false><<<grid, 128, 0, stream>>>(qkv, mask, rot, nullptr, out);
    }
}

// Round 17
// 94.494 us; speedup vs baseline: 1.7979x; 1.0447x over previous
//
#include <hip/hip_runtime.h>

#define NTOK 49
#define NH 4
#define HD 32
#define CIN 384
#define NW 64
#define NPAD 64
#define SCALE_F 0.1767766952966369f

typedef _Float16 f16x8 __attribute__((ext_vector_type(8)));
typedef float f32x16 __attribute__((ext_vector_type(16)));
typedef __fp16 fp16x2 __attribute__((ext_vector_type(2)));

__device__ __forceinline__ unsigned int pkh(float a, float b) {
    fp16x2 h = __builtin_amdgcn_cvt_pkrtz(a, b);
    return __builtin_bit_cast(unsigned int, h);
}

__device__ __forceinline__ void gload16(const float* g, float* l) {
    __builtin_amdgcn_global_load_lds(
        (const __attribute__((address_space(1))) void*)g,
        (__attribute__((address_space(3))) void*)l, 16, 0, 0);
}

// Grouped-quad combined mask: cmQ[wh][jg][i] = float4{ cm(j=4jg+k, i), k=0..3 }
// where cm(j,i) = mask[h][i][j] + rot[w][i][j]; j>=49 -> -1e30, i>=49 -> 0.
__global__ __launch_bounds__(64) void prep_cmask(
    const float* __restrict__ mask,
    const float* __restrict__ rot,
    float* __restrict__ cmQ)
{
    const int bx = blockIdx.x;          // 0..1023
    const int wh = bx >> 2;             // w*4 + h
    const int qt = bx & 3;              // j-quarter
    const int w = wh >> 2, h = wh & 3;
    const int i = threadIdx.x;          // 0..63
    #pragma unroll
    for (int g = 0; g < 4; ++g) {
        const int jg = qt * 4 + g;
        float4 v;
        float* vp = reinterpret_cast<float*>(&v);
        #pragma unroll
        for (int k = 0; k < 4; ++k) {
            const int j = 4 * jg + k;
            float val;
            if (j >= NTOK) val = -1e30f;
            else if (i >= NTOK) val = 0.f;
            else val = mask[(h * NTOK + i) * NTOK + j] + rot[(w * NTOK + i) * NTOK + j];
            vp[k] = val;
        }
        *reinterpret_cast<float4*>(&cmQ[((size_t)(wh * 16 + jg) * 64 + i) * 4]) = v;
    }
}

// R16 structure + V staged via fire-and-forget global_load_lds (f32 [64][32]
// linear; column reads are conflict-free: bank = l31). Q/K staged with the
// chunk-XOR swizzle (pre-swizzled global source, linear LDS dest). cm loads are
// 8 x b128 from grouped-quad cmQ. V rows 49..55 clamp to row 48 (finite; P=0
// there), rows 56..63 zero-filled (0 x NaN = NaN hazard via MFMA).
// Wave it owns query-half it; S^T=K*Q^T via mfma_32x32x16_f16
// (C: col=i=lane&31, row=j=(r&3)+8*(r>>2)+4*hl+32*jt); softmax lane-local +
// shfl_xor(32); P packed via cvt_pkrtz + one lane^32 exchange (R9 verbatim).
template<bool USE_CM>
__global__ __launch_bounds__(128) void win_attn_mfma(
    const float* __restrict__ qkv,
    const float* __restrict__ mask,
    const float* __restrict__ rot,
    const float* __restrict__ cmQ,
    float* __restrict__ out)
{
    const int h = blockIdx.x & 3;
    const int b = blockIdx.x >> 2;
    const int w = b & (NW - 1);
    const int tid = threadIdx.x;
    const int it = tid >> 6;            // wave id = query-half (0 stages Q, 1 stages K)
    const int lane = tid & 63;
    const int l31 = lane & 31;
    const int hl = lane >> 5;
    const int i = l31 + 32 * it;

    __shared__ float Qf[NPAD * 32];     // f32, swizzled-chunk layout
    __shared__ float Kf[NPAD * 32];
    __shared__ float Vf[NPAD * 32];     // f32, linear layout

    // ---- zero-fill rows 56..63 (floats 1792..2047) of all three arrays ----
    {
        const float4 z4 = make_float4(0.f, 0.f, 0.f, 0.f);
        if (tid < 64) {
            *reinterpret_cast<float4*>(&Qf[1792 + tid * 4]) = z4;
            *reinterpret_cast<float4*>(&Vf[1792 + tid * 4]) = z4;
        } else {
            *reinterpret_cast<float4*>(&Kf[1792 + (tid - 64) * 4]) = z4;
        }
    }

    // ---- fire-and-forget staging ----
    {
        const int row_l = lane >> 3;            // 0..7
        const int clog = (lane & 7) ^ row_l;    // pre-swizzled source chunk (Q/K)
        const float* srcbase = qkv + (size_t)b * (NTOK * CIN)
                             + (it ? 128 : 0) + h * HD + clog * 4;
        float* dst = it ? Kf : Qf;
        #pragma unroll
        for (int g = 0; g < 7; ++g) {
            const int srcrow = (8 * g + row_l < NTOK) ? (8 * g + row_l) : 48;
            gload16(srcbase + (size_t)srcrow * CIN, dst + g * 256);
        }
        // V: linear dest, no swizzle; wave0 takes even g, wave1 odd g.
        const float* vsrc = qkv + (size_t)b * (NTOK * CIN)
                          + 256 + h * HD + (lane & 7) * 4;
        #pragma unroll
        for (int g = it; g < 7; g += 2) {
            const int srcrow = (8 * g + row_l < NTOK) ? (8 * g + row_l) : 48;
            gload16(vsrc + (size_t)srcrow * CIN, Vf + g * 256);
        }
    }

    // ---- combined mask values: 8 x float4 (latency rides under stage drain) ----
    float cm[2][16];
    if (USE_CM) {
        const float* base4 = cmQ + (size_t)(w * 4 + h) * 16 * 256;  // 16 jg x 64 i x 4
        #pragma unroll
        for (int jt = 0; jt < 2; ++jt) {
            #pragma unroll
            for (int rq = 0; rq < 4; ++rq) {
                const int jg = 8 * jt + 2 * rq + hl;
                const float4 c = *reinterpret_cast<const float4*>(&base4[(jg * 64 + i) * 4]);
                cm[jt][4 * rq + 0] = c.x;
                cm[jt][4 * rq + 1] = c.y;
                cm[jt][4 * rq + 2] = c.z;
                cm[jt][4 * rq + 3] = c.w;
            }
        }
    } else {
        #pragma unroll
        for (int jt = 0; jt < 2; ++jt) {
            #pragma unroll
            for (int r = 0; r < 16; ++r) {
                const int j = (r & 3) + 8 * (r >> 2) + 4 * hl + 32 * jt;
                float v;
                if (j >= NTOK) v = -1e30f;
                else if (i >= NTOK) v = 0.f;
                else v = mask[(h * NTOK + i) * NTOK + j] + rot[(w * NTOK + i) * NTOK + j];
                cm[jt][r] = v;
            }
        }
    }

    __syncthreads();

    // ---- fragments from LDS (swizzled chunks), cvt to f16 at build ----
    auto ldfrag = [&](const float* L, int row, int ks, bool scaled) -> f16x8 {
        const int swz = row & 7;
        const int c0 = ks * 4 + hl * 2;
        const float4 a  = *reinterpret_cast<const float4*>(&L[row * 32 + ((c0)     ^ swz) * 4]);
        const float4 bb = *reinterpret_cast<const float4*>(&L[row * 32 + ((c0 + 1) ^ swz) * 4]);
        uint4 u;
        if (scaled) {
            u.x = pkh(a.x * SCALE_F, a.y * SCALE_F);
            u.y = pkh(a.z * SCALE_F, a.w * SCALE_F);
            u.z = pkh(bb.x * SCALE_F, bb.y * SCALE_F);
            u.w = pkh(bb.z * SCALE_F, bb.w * SCALE_F);
        } else {
            u.x = pkh(a.x, a.y);
            u.y = pkh(a.z, a.w);
            u.z = pkh(bb.x, bb.y);
            u.w = pkh(bb.z, bb.w);
        }
        return __builtin_bit_cast(f16x8, u);
    };

    f16x8 ka[2][2], qa[2];
    #pragma unroll
    for (int kt = 0; kt < 2; ++kt) {
        #pragma unroll
        for (int ks = 0; ks < 2; ++ks) {
            ka[kt][ks] = ldfrag(Kf, l31 + 32 * kt, ks, false);
        }
    }
    #pragma unroll
    for (int ks = 0; ks < 2; ++ks) {
        qa[ks] = ldfrag(Qf, l31 + 32 * it, ks, true);
    }

    // ---- S^T = K * Q^T for this half ----
    f32x16 acc[2];
    #pragma unroll
    for (int jt = 0; jt < 2; ++jt) {
        f32x16 a;
        #pragma unroll
        for (int r = 0; r < 16; ++r) a[r] = 0.f;
        a = __builtin_amdgcn_mfma_f32_32x32x16_f16(ka[jt][0], qa[0], a, 0, 0, 0);
        a = __builtin_amdgcn_mfma_f32_32x32x16_f16(ka[jt][1], qa[1], a, 0, 0, 0);
        acc[jt] = a;
    }

    // ---- + mask, softmax over j (32 lane-local + lane^32 partner) ----
    float m = -3e38f;
    #pragma unroll
    for (int jt = 0; jt < 2; ++jt) {
        #pragma unroll
        for (int r = 0; r < 16; ++r) {
            acc[jt][r] += cm[jt][r];
            m = fmaxf(m, acc[jt][r]);
        }
    }
    m = fmaxf(m, __shfl_xor(m, 32));
    float s = 0.f;
    #pragma unroll
    for (int jt = 0; jt < 2; ++jt) {
        #pragma unroll
        for (int r = 0; r < 16; ++r) {
            const float e = __expf(acc[jt][r] - m);
            acc[jt][r] = e;
            s += e;
        }
    }
    s += __shfl_xor(s, 32);
    const float inv = 1.f / s;
    #pragma unroll
    for (int jt = 0; jt < 2; ++jt) {
        #pragma unroll
        for (int r = 0; r < 16; ++r) acc[jt][r] *= inv;
    }

    // ---- O = P * V (V fragments from LDS: bank = l31, conflict-free) ----
    f32x16 oacc;
    #pragma unroll
    for (int r = 0; r < 16; ++r) oacc[r] = 0.f;

    #pragma unroll
    for (int ks = 0; ks < 4; ++ks) {
        unsigned int vd[4];
        #pragma unroll
        for (int ep = 0; ep < 4; ++ep) {
            const int j0 = 16 * ks + 8 * hl + 2 * ep;
            vd[ep] = pkh(Vf[j0 * 32 + l31], Vf[(j0 + 1) * 32 + l31]);
        }
        uint4 vu = make_uint4(vd[0], vd[1], vd[2], vd[3]);
        const f16x8 vb = __builtin_bit_cast(f16x8, vu);

        const int jt = ks >> 1;
        const int r8 = 8 * (ks & 1);
        const unsigned lo0 = pkh(acc[jt][r8 + 0], acc[jt][r8 + 1]);
        const unsigned lo1 = pkh(acc[jt][r8 + 2], acc[jt][r8 + 3]);
        const unsigned hi0 = pkh(acc[jt][r8 + 4], acc[jt][r8 + 5]);
        const unsigned hi1 = pkh(acc[jt][r8 + 6], acc[jt][r8 + 7]);
        const unsigned x0 = hl ? lo0 : hi0;
        const unsigned x1 = hl ? lo1 : hi1;
        const unsigned y0 = (unsigned)__shfl_xor((int)x0, 32);
        const unsigned y1 = (unsigned)__shfl_xor((int)x1, 32);
        uint4 pu;
        pu.x = hl ? y0 : lo0;
        pu.y = hl ? y1 : lo1;
        pu.z = hl ? hi0 : y0;
        pu.w = hl ? hi1 : y1;
        const f16x8 pa = __builtin_bit_cast(f16x8, pu);
        oacc = __builtin_amdgcn_mfma_f32_32x32x16_f16(pa, vb, oacc, 0, 0, 0);
    }

    // ---- store this half: O[i][d], d = l31 ----
    float* obase = out + (size_t)b * NTOK * (NH * HD) + h * HD + l31;
    #pragma unroll
    for (int r = 0; r < 16; ++r) {
        const int io = (r & 3) + 8 * (r >> 2) + 4 * hl + 32 * it;
        if (io < NTOK) obase[(size_t)io * (NH * HD)] = oacc[r];
    }
}

extern "C" void kernel_launch(void* const* d_in, const int* in_sizes, int n_in,
                              void* d_out, int out_size, void* d_ws, size_t ws_size,
                              hipStream_t stream) {
    const float* qkv  = (const float*)d_in[0];
    const float* mask = (const float*)d_in[1];
    const float* rot  = (const float*)d_in[2];
    float* out = (float*)d_out;

    const int Btot = in_sizes[0] / (NTOK * CIN);  // 4096
    dim3 grid(Btot * NH);

    const size_t cm_bytes = (size_t)NW * NH * 16 * 64 * 4 * sizeof(float);  // 4 MiB
    if (ws_size >= cm_bytes && d_ws != nullptr) {
        float* cmQ = (float*)d_ws;
        prep_cmask<<<dim3(NW * NH * 4), 64, 0, stream>>>(mask, rot, cmQ);
        win_attn_mfma<true><<<grid, 128, 0, stream>>>(qkv, mask, rot, cmQ, out);
    } else {
        win_attn_mfma<false><<<grid, 128, 0, stream>>>(qkv, mask, rot, nullptr, out);
    }
}